// Round 3
// baseline (469.764 us; speedup 1.0000x reference)
//
#include <hip/hip_runtime.h>

#define NJ 24
#define HIDN 7
#define FEATN 6

// Weights are wave-uniform and indexed with compile-time constants, so the
// compiler emits s_load (scalar cache -> SGPR) and v_fma_f32 with an SGPR
// operand. No LDS, no vector loads for weights, no __syncthreads.
__global__ __launch_bounds__(256)
void structure_encoder_kernel(const float* __restrict__ x,
                              const float* __restrict__ W1,
                              const float* __restrict__ b1,
                              const float* __restrict__ W2,
                              const float* __restrict__ b2,
                              float* __restrict__ out, int B)
{
    int row = blockIdx.x * blockDim.x + threadIdx.x;
    if (row >= B) return;

    // Load the 24 input floats for this row as 6 float4 (row base 96B-aligned).
    float xv[NJ];
    const float4* xp = reinterpret_cast<const float4*>(x + (size_t)row * NJ);
    #pragma unroll
    for (int q = 0; q < 6; ++q) {
        float4 t = xp[q];
        xv[q * 4 + 0] = t.x; xv[q * 4 + 1] = t.y;
        xv[q * 4 + 2] = t.z; xv[q * 4 + 3] = t.w;
    }

    float feat[NJ][FEATN];   // fully-unrolled chain -> compile-time indices -> registers
    float* orow = out + (size_t)row * (NJ * FEATN);

    constexpr int parents[NJ] = {-1,0,0,0,1,2,3,4,5,6,7,8,9,9,9,12,13,14,16,17,18,19,20,21};

    #pragma unroll
    for (int j = 0; j < NJ; ++j) {
        const float* W1j = W1 + j * (HIDN * HIDN);
        const float* b1j = b1 + j * HIDN;
        const float* W2j = W2 + j * (FEATN * HIDN);
        const float* b2j = b2 + j * FEATN;

        float inp[HIDN];
        inp[0] = xv[j];
        const int p = parents[j];
        #pragma unroll
        for (int c = 0; c < FEATN; ++c)
            inp[1 + c] = (p < 0) ? 0.f : feat[p][c];

        float h[HIDN];
        #pragma unroll
        for (int r = 0; r < HIDN; ++r) {
            float acc = b1j[r];
            #pragma unroll
            for (int c = 0; c < HIDN; ++c)
                acc = fmaf(W1j[r * HIDN + c], inp[c], acc);
            h[r] = fmaxf(acc, 0.f);
        }

        #pragma unroll
        for (int r = 0; r < FEATN; ++r) {
            float acc = b2j[r];
            #pragma unroll
            for (int c = 0; c < HIDN; ++c)
                acc = fmaf(W2j[r * HIDN + c], h[c], acc);
            feat[j][r] = fmaxf(acc, 0.f);
        }

        // Store pairs of joints: 12 floats starting at (j-1)*6, 16B-aligned.
        if (j & 1) {
            float4* dst = reinterpret_cast<float4*>(orow + (j - 1) * FEATN);
            float4 v0 = make_float4(feat[j-1][0], feat[j-1][1], feat[j-1][2], feat[j-1][3]);
            float4 v1 = make_float4(feat[j-1][4], feat[j-1][5], feat[j][0],   feat[j][1]);
            float4 v2 = make_float4(feat[j][2],   feat[j][3],   feat[j][4],   feat[j][5]);
            dst[0] = v0; dst[1] = v1; dst[2] = v2;
        }
    }
}

extern "C" void kernel_launch(void* const* d_in, const int* in_sizes, int n_in,
                              void* d_out, int out_size, void* d_ws, size_t ws_size,
                              hipStream_t stream) {
    const float* x  = (const float*)d_in[0];
    const float* W1 = (const float*)d_in[1];
    const float* b1 = (const float*)d_in[2];
    const float* W2 = (const float*)d_in[3];
    const float* b2 = (const float*)d_in[4];
    float* out = (float*)d_out;

    const int B = in_sizes[0] / NJ;
    const int block = 256;
    const int grid = (B + block - 1) / block;
    structure_encoder_kernel<<<grid, block, 0, stream>>>(x, W1, b1, W2, b2, out, B);
}

// Round 4
// 465.556 us; speedup vs baseline: 1.0090x; 1.0090x over previous
//
#include <hip/hip_runtime.h>

#define NJ 24
#define HIDN 7
#define FEATN 6

// Weights are wave-uniform with compile-time offsets -> s_load to SGPRs.
// Output stores are batched into bursts of 8 joints (48 floats = 192 B =
// exactly 3 full 64-B cache lines, issued back-to-back) so L2 lines complete
// immediately -> no partial-line eviction -> no HBM read-modify-write
// write amplification.
__global__ __launch_bounds__(256)
void structure_encoder_kernel(const float* __restrict__ x,
                              const float* __restrict__ W1,
                              const float* __restrict__ b1,
                              const float* __restrict__ W2,
                              const float* __restrict__ b2,
                              float* __restrict__ out, int B)
{
    int row = blockIdx.x * blockDim.x + threadIdx.x;
    if (row >= B) return;

    // Load the 24 input floats for this row as 6 float4 (row base 96B-aligned).
    float xv[NJ];
    const float4* xp = reinterpret_cast<const float4*>(x + (size_t)row * NJ);
    #pragma unroll
    for (int q = 0; q < 6; ++q) {
        float4 t = xp[q];
        xv[q * 4 + 0] = t.x; xv[q * 4 + 1] = t.y;
        xv[q * 4 + 2] = t.z; xv[q * 4 + 3] = t.w;
    }

    float feat[NJ][FEATN];   // fully-unrolled chain -> compile-time indices -> registers
    float4* orow4 = reinterpret_cast<float4*>(out + (size_t)row * (NJ * FEATN));

    constexpr int parents[NJ] = {-1,0,0,0,1,2,3,4,5,6,7,8,9,9,9,12,13,14,16,17,18,19,20,21};

    #pragma unroll
    for (int j = 0; j < NJ; ++j) {
        const float* W1j = W1 + j * (HIDN * HIDN);
        const float* b1j = b1 + j * HIDN;
        const float* W2j = W2 + j * (FEATN * HIDN);
        const float* b2j = b2 + j * FEATN;

        float inp[HIDN];
        inp[0] = xv[j];
        const int p = parents[j];
        #pragma unroll
        for (int c = 0; c < FEATN; ++c)
            inp[1 + c] = (p < 0) ? 0.f : feat[p][c];

        float h[HIDN];
        #pragma unroll
        for (int r = 0; r < HIDN; ++r) {
            float acc = b1j[r];
            #pragma unroll
            for (int c = 0; c < HIDN; ++c)
                acc = fmaf(W1j[r * HIDN + c], inp[c], acc);
            h[r] = fmaxf(acc, 0.f);
        }

        #pragma unroll
        for (int r = 0; r < FEATN; ++r) {
            float acc = b2j[r];
            #pragma unroll
            for (int c = 0; c < HIDN; ++c)
                acc = fmaf(W2j[r * HIDN + c], h[c], acc);
            feat[j][r] = fmaxf(acc, 0.f);
        }

        // Burst-store 8 completed joints: 48 floats = 12 dwordx4 back-to-back,
        // covering 3 complete 64-B lines per row (row base is 576B = 9 lines,
        // burst b covers lines 3b..3b+2 exactly).
        if (j == 7 || j == 15 || j == 23) {
            const int burst = (j - 7) / 8;        // 0,1,2 (compile-time)
            #pragma unroll
            for (int q = 0; q < 12; ++q) {
                const int f0 = burst * 48 + q * 4; // flat float offset in row
                float4 v;
                v.x = feat[(f0 + 0) / FEATN][(f0 + 0) % FEATN];
                v.y = feat[(f0 + 1) / FEATN][(f0 + 1) % FEATN];
                v.z = feat[(f0 + 2) / FEATN][(f0 + 2) % FEATN];
                v.w = feat[(f0 + 3) / FEATN][(f0 + 3) % FEATN];
                orow4[burst * 12 + q] = v;
            }
        }
    }
}

extern "C" void kernel_launch(void* const* d_in, const int* in_sizes, int n_in,
                              void* d_out, int out_size, void* d_ws, size_t ws_size,
                              hipStream_t stream) {
    const float* x  = (const float*)d_in[0];
    const float* W1 = (const float*)d_in[1];
    const float* b1 = (const float*)d_in[2];
    const float* W2 = (const float*)d_in[3];
    const float* b2 = (const float*)d_in[4];
    float* out = (float*)d_out;

    const int B = in_sizes[0] / NJ;
    const int block = 256;
    const int grid = (B + block - 1) / block;
    structure_encoder_kernel<<<grid, block, 0, stream>>>(x, W1, b1, W2, b2, out, B);
}

// Round 5
// 409.391 us; speedup vs baseline: 1.1475x; 1.1372x over previous
//
#include <hip/hip_runtime.h>

#define NJ 24
#define HIDN 7
#define FEATN 6

// One lane per row; all global I/O goes through a wave-private LDS transpose
// so every global instruction writes/reads full cache lines:
//  - x: wave loads its contiguous 6144B region coalesced, transposes in LDS.
//  - out: bursts of 8 joints (48 floats = 12 float4/row); lane dumps to LDS
//    (stride 13 f4 -> bank-group (5r+s)%8 fully spread, conflict-free), then
//    the wave stores 192B row-chunks with consecutive lanes on consecutive
//    float4s (~17 full 64B lines per store instr vs 64 partial lines before).
// No __syncthreads needed: each wave owns its buffer; compiler orders ds ops.
__global__ __launch_bounds__(256)
void structure_encoder_kernel(const float* __restrict__ x,
                              const float* __restrict__ W1,
                              const float* __restrict__ b1,
                              const float* __restrict__ W2,
                              const float* __restrict__ b2,
                              float* __restrict__ out, int B)
{
    __shared__ float4 obuf[4][64 * 13];   // 53248 B: per-wave 64 rows x (12+1 pad) f4

    const int tid  = threadIdx.x;
    const int wv   = tid >> 6;
    const int lane = tid & 63;
    float4* buf = obuf[wv];

    const long long rowBase = (long long)blockIdx.x * 256 + (long long)wv * 64;

    // ---- coalesced x load + wave-private transpose ----
    const float4* x4 = reinterpret_cast<const float4*>(x);
    const long long xMax = (long long)B * 6 - 1;           // last valid f4 index
    #pragma unroll
    for (int k = 0; k < 6; ++k) {
        const int lo = lane + 64 * k;                      // 0..383 local f4
        long long g = rowBase * 6 + lo;
        if (g > xMax) g = xMax;                            // tail clamp (never stored)
        const float4 v = x4[g];
        const int r = lo / 6, s = lo - 6 * r;
        buf[r * 13 + s] = v;
    }
    float xv[NJ];
    #pragma unroll
    for (int s = 0; s < 6; ++s) {
        const float4 v = buf[lane * 13 + s];
        xv[4*s+0] = v.x; xv[4*s+1] = v.y; xv[4*s+2] = v.z; xv[4*s+3] = v.w;
    }

    float feat[NJ][FEATN];                 // compile-time indices -> registers
    float4* out4 = reinterpret_cast<float4*>(out);

    constexpr int parents[NJ] = {-1,0,0,0,1,2,3,4,5,6,7,8,9,9,9,12,13,14,16,17,18,19,20,21};

    #pragma unroll
    for (int j = 0; j < NJ; ++j) {
        const float* W1j = W1 + j * (HIDN * HIDN);
        const float* b1j = b1 + j * HIDN;
        const float* W2j = W2 + j * (FEATN * HIDN);
        const float* b2j = b2 + j * FEATN;

        float inp[HIDN];
        inp[0] = xv[j];
        const int p = parents[j];
        #pragma unroll
        for (int c = 0; c < FEATN; ++c)
            inp[1 + c] = (p < 0) ? 0.f : feat[p][c];

        float h[HIDN];
        #pragma unroll
        for (int r = 0; r < HIDN; ++r) {
            float acc = b1j[r];
            #pragma unroll
            for (int c = 0; c < HIDN; ++c)
                acc = fmaf(W1j[r * HIDN + c], inp[c], acc);
            h[r] = fmaxf(acc, 0.f);
        }
        #pragma unroll
        for (int r = 0; r < FEATN; ++r) {
            float acc = b2j[r];
            #pragma unroll
            for (int c = 0; c < HIDN; ++c)
                acc = fmaf(W2j[r * HIDN + c], h[c], acc);
            feat[j][r] = fmaxf(acc, 0.f);
        }

        // ---- burst: LDS transpose + full-line global store ----
        if (j == 7 || j == 15 || j == 23) {
            const int b = j / 8;                           // 0,1,2 compile-time
            #pragma unroll
            for (int q = 0; q < 12; ++q) {                 // lane's 48 floats -> LDS
                float4 v;
                v.x = feat[b*8 + (4*q+0)/6][(4*q+0)%6];
                v.y = feat[b*8 + (4*q+1)/6][(4*q+1)%6];
                v.z = feat[b*8 + (4*q+2)/6][(4*q+2)%6];
                v.w = feat[b*8 + (4*q+3)/6][(4*q+3)%6];
                buf[lane * 13 + q] = v;
            }
            #pragma unroll
            for (int k = 0; k < 12; ++k) {                 // wave stores 12288 B
                const int o  = lane + 64 * k;              // 0..767
                const int rr = o / 12, s = o - 12 * rr;
                if (rowBase + rr < (long long)B)
                    out4[(rowBase + rr) * 36 + b * 12 + s] = buf[rr * 13 + s];
            }
        }
    }
}

extern "C" void kernel_launch(void* const* d_in, const int* in_sizes, int n_in,
                              void* d_out, int out_size, void* d_ws, size_t ws_size,
                              hipStream_t stream) {
    const float* x  = (const float*)d_in[0];
    const float* W1 = (const float*)d_in[1];
    const float* b1 = (const float*)d_in[2];
    const float* W2 = (const float*)d_in[3];
    const float* b2 = (const float*)d_in[4];
    float* out = (float*)d_out;

    const int B = in_sizes[0] / NJ;
    const int block = 256;
    const int grid = (B + block - 1) / block;
    structure_encoder_kernel<<<grid, block, 0, stream>>>(x, W1, b1, W2, b2, out, B);
}